// Round 1
// baseline (808.995 us; speedup 1.0000x reference)
//
#include <hip/hip_runtime.h>
#include <cstdint>
#include <cstddef>

// ---------------------------------------------------------------------------
// RNN (leaky-integrator, 12 steps, B=1024) on gfx950.
//  - h-path hoisted: u_t = x_t + 0.75*u_{t-1}  (prefix scan, elementwise)
//    h_t = 0.25*(u_{t-1} @ w_oh) + (1-0.75^t)*b_h ; a_h_t = sigmoid(h_t)
//    => one big GEMM [11264 x 1024] @ [1024 x 1024], fused sigmoid epilogue.
//  - 12 sequential fused step GEMMs: out cols [0,1024) = p (K=2560 over
//    [a_h|a_p|a_c]), cols [1024,1536) = c-pre (K=1024 over a_p).
//    Epilogue: leaky blend (fp32 state), sigmoid, f16 activation store,
//    fp32 output store for t>=8. Activation buffers ping-pong per step.
//  - fp16 MFMA (16x16x32), fp32 accum. 64x64 single-wave blocks, BK=64,
//    global_load_lds width-16 staging, XOR-swizzled LDS to avoid bank
//    conflicts on column-pattern ds_read_b128.
// ---------------------------------------------------------------------------

typedef _Float16 half8 __attribute__((ext_vector_type(8)));
typedef float floatx4 __attribute__((ext_vector_type(4)));

__device__ __forceinline__ void async_cp16(const void* g, void* l) {
  __builtin_amdgcn_global_load_lds(
      (const __attribute__((address_space(1))) void*)g,
      (__attribute__((address_space(3))) void*)l, 16, 0, 0);
}

__device__ __forceinline__ float sigmoidf_(float x) {
  return 1.f / (1.f + __expf(-x));
}

// ---- transpose fp32 [K][N] -> f16 dst[n][k_off + k], dst leading dim dst_ld
__global__ __launch_bounds__(256) void k_transpose(
    const float* __restrict__ src, int K, int N,
    _Float16* __restrict__ dst, int dst_ld, int k_off) {
  __shared__ float tile[64][65];
  const int k0 = blockIdx.y * 64, n0 = blockIdx.x * 64;
  const int tx = threadIdx.x & 63, ty = threadIdx.x >> 6;
#pragma unroll
  for (int j = 0; j < 16; ++j) {
    int kr = j * 4 + ty;
    tile[kr][tx] = src[(size_t)(k0 + kr) * N + n0 + tx];
  }
  __syncthreads();
#pragma unroll
  for (int j = 0; j < 16; ++j) {
    int nr = j * 4 + ty;
    dst[(size_t)(n0 + nr) * dst_ld + k_off + k0 + tx] = (_Float16)tile[tx][nr];
  }
}

// ---- prefix scan over t of x (decay 0.75) -> U f16 [11][1024][1024]; inits
__global__ __launch_bounds__(256) void k_prep(
    const float* __restrict__ x, _Float16* __restrict__ U,
    _Float16* __restrict__ AH0, _Float16* __restrict__ AP0,
    _Float16* __restrict__ AC0, float* __restrict__ Pst,
    float* __restrict__ Cst) {
  const int id = blockIdx.x * 256 + threadIdx.x;  // 0 .. 1M-1
  const int b = id >> 10, i = id & 1023;
  const float* xb = x + (size_t)b * 12 * 1024 + i;
  float g = 0.f;
#pragma unroll
  for (int t = 0; t < 11; ++t) {
    g = xb[t * 1024] + 0.75f * g;
    U[(size_t)t * 1048576 + id] = (_Float16)g;
  }
  AH0[id] = (_Float16)0.5f;
  AP0[id] = (_Float16)0.5f;
  Pst[id] = 0.f;
  if (i < 512) {
    const int cid = b * 512 + i;
    AC0[cid] = (_Float16)0.5f;
    Cst[cid] = 0.f;
  }
}

// ---- hoisted h GEMM: C[11264 x 1024] = U @ w_oh (B^T layout), sigmoid epi
__global__ __launch_bounds__(64) void k_gemm_oh(
    const _Float16* __restrict__ U, const _Float16* __restrict__ WohT,
    const float* __restrict__ bias_h, _Float16* __restrict__ AH) {
  __shared__ __align__(16) _Float16 sA[4096];
  __shared__ __align__(16) _Float16 sB[4096];
  const int lane = threadIdx.x;
  const int mBase = blockIdx.y * 64;
  const int nBase = blockIdx.x * 64;
  const int r16 = lane & 15, quad = lane >> 4;
  const int mrow = lane >> 3;
  const int gsw = ((lane & 7) ^ (mrow & 7)) * 8;  // XOR-swizzled k granule
  const floatx4 zero = {0.f, 0.f, 0.f, 0.f};
  floatx4 acc[4][4];
#pragma unroll
  for (int i = 0; i < 4; ++i)
#pragma unroll
    for (int j = 0; j < 4; ++j) acc[i][j] = zero;

  const _Float16* A0 = U + (size_t)mBase * 1024;
  const _Float16* B0 = WohT + (size_t)nBase * 1024;
  for (int kt = 0; kt < 16; ++kt) {
    const int k0 = kt * 64;
#pragma unroll
    for (int q = 0; q < 8; ++q)
      async_cp16(A0 + (size_t)(q * 8 + mrow) * 1024 + k0 + gsw, sA + q * 512);
#pragma unroll
    for (int q = 0; q < 8; ++q)
      async_cp16(B0 + (size_t)(q * 8 + mrow) * 1024 + k0 + gsw, sB + q * 512);
    __builtin_amdgcn_s_waitcnt(0);
    __syncthreads();
#pragma unroll
    for (int kk = 0; kk < 2; ++kk) {
      half8 af[4], bf[4];
#pragma unroll
      for (int i = 0; i < 4; ++i) {
        int r = i * 16 + r16;
        af[i] = *(const half8*)&sA[r * 64 + (((kk * 4 + quad) ^ (r & 7)) * 8)];
      }
#pragma unroll
      for (int j = 0; j < 4; ++j) {
        int r = j * 16 + r16;
        bf[j] = *(const half8*)&sB[r * 64 + (((kk * 4 + quad) ^ (r & 7)) * 8)];
      }
#pragma unroll
      for (int i = 0; i < 4; ++i)
#pragma unroll
        for (int j = 0; j < 4; ++j)
          acc[i][j] =
              __builtin_amdgcn_mfma_f32_16x16x32_f16(af[i], bf[j], acc[i][j], 0, 0, 0);
    }
    __syncthreads();
  }
  const int tm1 = mBase >> 10;  // 0..10, actual t = tm1+1
  const float beta = 1.f - __powf(0.75f, (float)(tm1 + 1));
  const int bofs = mBase & 1023;
  _Float16* AHt = AH + (size_t)(tm1 + 1) * 1048576;
#pragma unroll
  for (int i = 0; i < 4; ++i) {
#pragma unroll
    for (int j = 0; j < 4; ++j) {
      const int n = nBase + j * 16 + r16;
#pragma unroll
      for (int r = 0; r < 4; ++r) {
        const int b = bofs + i * 16 + quad * 4 + r;
        const float h = 0.25f * acc[i][j][r] + beta * bias_h[n];
        AHt[(size_t)b * 1024 + n] = (_Float16)sigmoidf_(h);
      }
    }
  }
}

// ---- one recurrent step: cols [0,1024)=p (K=2560), cols [1024,1536)=c (K=1024)
__global__ __launch_bounds__(64) void k_step(
    const _Float16* __restrict__ AHt, const _Float16* __restrict__ APc,
    const _Float16* __restrict__ ACc, _Float16* __restrict__ APn,
    _Float16* __restrict__ ACn, const _Float16* __restrict__ Wp,
    const _Float16* __restrict__ Wc, const float* __restrict__ bias_p,
    const float* __restrict__ bias_c, float* __restrict__ Pst,
    float* __restrict__ Cst, float* __restrict__ out_t) {
  __shared__ __align__(16) _Float16 sA[4096];
  __shared__ __align__(16) _Float16 sB[4096];
  const int lane = threadIdx.x;
  const int mBase = blockIdx.y * 64;
  const bool isP = blockIdx.x < 16;
  const int nBase = isP ? blockIdx.x * 64 : (blockIdx.x - 16) * 64;
  const int r16 = lane & 15, quad = lane >> 4;
  const int mrow = lane >> 3;
  const int gsw = ((lane & 7) ^ (mrow & 7)) * 8;
  const floatx4 zero = {0.f, 0.f, 0.f, 0.f};
  floatx4 acc[4][4];
#pragma unroll
  for (int i = 0; i < 4; ++i)
#pragma unroll
    for (int j = 0; j < 4; ++j) acc[i][j] = zero;

  const int KT = isP ? 40 : 16;
  const _Float16* Bbase =
      isP ? Wp + (size_t)nBase * 2560 : Wc + (size_t)nBase * 1024;
  const int ldB = isP ? 2560 : 1024;

  for (int kt = 0; kt < KT; ++kt) {
    const int k0 = kt * 64;
    const _Float16* Asrc;
    int ldA, kA;
    if (!isP) {
      Asrc = APc; ldA = 1024; kA = k0;
    } else if (k0 < 1024) {
      Asrc = AHt; ldA = 1024; kA = k0;
    } else if (k0 < 2048) {
      Asrc = APc; ldA = 1024; kA = k0 - 1024;
    } else {
      Asrc = ACc; ldA = 512; kA = k0 - 2048;
    }
#pragma unroll
    for (int q = 0; q < 8; ++q)
      async_cp16(Asrc + (size_t)(mBase + q * 8 + mrow) * ldA + kA + gsw,
                 sA + q * 512);
#pragma unroll
    for (int q = 0; q < 8; ++q)
      async_cp16(Bbase + (size_t)(q * 8 + mrow) * ldB + k0 + gsw, sB + q * 512);
    __builtin_amdgcn_s_waitcnt(0);
    __syncthreads();
#pragma unroll
    for (int kk = 0; kk < 2; ++kk) {
      half8 af[4], bf[4];
#pragma unroll
      for (int i = 0; i < 4; ++i) {
        int r = i * 16 + r16;
        af[i] = *(const half8*)&sA[r * 64 + (((kk * 4 + quad) ^ (r & 7)) * 8)];
      }
#pragma unroll
      for (int j = 0; j < 4; ++j) {
        int r = j * 16 + r16;
        bf[j] = *(const half8*)&sB[r * 64 + (((kk * 4 + quad) ^ (r & 7)) * 8)];
      }
#pragma unroll
      for (int i = 0; i < 4; ++i)
#pragma unroll
        for (int j = 0; j < 4; ++j)
          acc[i][j] =
              __builtin_amdgcn_mfma_f32_16x16x32_f16(af[i], bf[j], acc[i][j], 0, 0, 0);
    }
    __syncthreads();
  }

  if (isP) {
#pragma unroll
    for (int i = 0; i < 4; ++i) {
#pragma unroll
      for (int j = 0; j < 4; ++j) {
        const int n = nBase + j * 16 + r16;
#pragma unroll
        for (int r = 0; r < 4; ++r) {
          const int b = mBase + i * 16 + quad * 4 + r;
          const size_t o = (size_t)b * 1024 + n;
          const float pn = 0.25f * (acc[i][j][r] + bias_p[n]) + 0.75f * Pst[o];
          Pst[o] = pn;
          const float a = sigmoidf_(pn);
          APn[o] = (_Float16)a;
          if (out_t) out_t[o] = a;
        }
      }
    }
  } else {
#pragma unroll
    for (int i = 0; i < 4; ++i) {
#pragma unroll
      for (int j = 0; j < 4; ++j) {
        const int n = nBase + j * 16 + r16;  // 0..511
#pragma unroll
        for (int r = 0; r < 4; ++r) {
          const int b = mBase + i * 16 + quad * 4 + r;
          const size_t o = (size_t)b * 512 + n;
          const float cn = 0.25f * (acc[i][j][r] + bias_c[n]) + 0.75f * Cst[o];
          Cst[o] = cn;
          ACn[o] = (_Float16)sigmoidf_(cn);
        }
      }
    }
  }
}

extern "C" void kernel_launch(void* const* d_in, const int* in_sizes, int n_in,
                              void* d_out, int out_size, void* d_ws,
                              size_t ws_size, hipStream_t stream) {
  const float* x      = (const float*)d_in[0];  // [1024,12,1024]
  const float* w_oh   = (const float*)d_in[1];  // [1024,1024]
  const float* w_hp   = (const float*)d_in[2];  // [1024,1024]
  const float* w_pp   = (const float*)d_in[3];  // [1024,1024]
  const float* w_pc   = (const float*)d_in[4];  // [1024,512]
  const float* w_cp   = (const float*)d_in[5];  // [512,1024]
  const float* bias_h = (const float*)d_in[6];
  const float* bias_p = (const float*)d_in[7];
  const float* bias_c = (const float*)d_in[8];
  float* out = (float*)d_out;

  uint8_t* p = (uint8_t*)d_ws;
  _Float16* Wp   = (_Float16*)p; p += (size_t)1024 * 2560 * 2;  // [n][k] k=2560
  _Float16* Wc   = (_Float16*)p; p += (size_t)512 * 1024 * 2;   // [n][k]
  _Float16* WohT = (_Float16*)p; p += (size_t)1024 * 1024 * 2;  // [n][k]
  _Float16* U    = (_Float16*)p; p += (size_t)11 * 1048576 * 2;
  _Float16* AH   = (_Float16*)p; p += (size_t)12 * 1048576 * 2;
  _Float16* AP0  = (_Float16*)p; p += (size_t)1048576 * 2;
  _Float16* AP1  = (_Float16*)p; p += (size_t)1048576 * 2;
  _Float16* AC0  = (_Float16*)p; p += (size_t)512 * 1024 * 2;
  _Float16* AC1  = (_Float16*)p; p += (size_t)512 * 1024 * 2;
  float* Pst = (float*)p; p += (size_t)1048576 * 4;
  float* Cst = (float*)p; p += (size_t)512 * 1024 * 4;

  const dim3 blk256(256), blk64(64);
  // weight repack (fp32 [K][N] -> f16 [N][K])
  k_transpose<<<dim3(16, 16), blk256, 0, stream>>>(w_hp, 1024, 1024, Wp, 2560, 0);
  k_transpose<<<dim3(16, 16), blk256, 0, stream>>>(w_pp, 1024, 1024, Wp, 2560, 1024);
  k_transpose<<<dim3(16, 8),  blk256, 0, stream>>>(w_cp, 512, 1024, Wp, 2560, 2048);
  k_transpose<<<dim3(8, 16),  blk256, 0, stream>>>(w_pc, 1024, 512, Wc, 1024, 0);
  k_transpose<<<dim3(16, 16), blk256, 0, stream>>>(w_oh, 1024, 1024, WohT, 1024, 0);
  // input scan + state init
  k_prep<<<4096, blk256, 0, stream>>>(x, U, AH, AP0, AC0, Pst, Cst);
  // hoisted h GEMM -> AH[1..11]
  k_gemm_oh<<<dim3(16, 176), blk64, 0, stream>>>(U, WohT, bias_h, AH);
  // 12 sequential steps
  for (int t = 0; t < 12; ++t) {
    const _Float16* APc = (t & 1) ? AP1 : AP0;
    _Float16* APn       = (t & 1) ? AP0 : AP1;
    const _Float16* ACc = (t & 1) ? AC1 : AC0;
    _Float16* ACn       = (t & 1) ? AC0 : AC1;
    float* ot = (t >= 8) ? out + (size_t)(t - 8) * 1048576 : (float*)nullptr;
    k_step<<<dim3(24, 16), blk64, 0, stream>>>(AH + (size_t)t * 1048576, APc,
                                               ACc, APn, ACn, Wp, Wc, bias_p,
                                               bias_c, Pst, Cst, ot);
  }
}

// Round 2
// 735.520 us; speedup vs baseline: 1.0999x; 1.0999x over previous
//
#include <hip/hip_runtime.h>
#include <cstdint>
#include <cstddef>

// ---------------------------------------------------------------------------
// RNN (leaky-integrator, 12 steps, B=1024) on gfx950.
//  - h-path hoisted: one GEMM [11264x1024] over decay-scanned inputs U.
//  - NEW: a_h @ w_hp hoisted too: Q_t = 0.25*(a_h_t @ w_hp + bias_p) for all
//    12 t in one GEMM [12288x1024]. Per-step K drops 2560 -> 1536.
//  - 12 sequential step GEMMs (single wave per block, 64x64 tile), now with
//    a BARRIER-FREE software pipeline: 3 LDS buffers, prefetch depth 2,
//    explicit s_waitcnt vmcnt(32/16/0). No __syncthreads at all.
//  - fp16 MFMA 16x16x32, fp32 accum, global_load_lds width-16 staging,
//    XOR-swizzled LDS granules (0 bank conflicts measured in R0).
// ---------------------------------------------------------------------------

typedef _Float16 half8 __attribute__((ext_vector_type(8)));
typedef float floatx4 __attribute__((ext_vector_type(4)));

__device__ __forceinline__ void async_cp16(const void* g, void* l) {
  __builtin_amdgcn_global_load_lds(
      (const __attribute__((address_space(1))) void*)g,
      (__attribute__((address_space(3))) void*)l, 16, 0, 0);
}

__device__ __forceinline__ float sigmoidf_(float x) {
  return 1.f / (1.f + __expf(-x));
}

// ---- transpose fp32 [K][N] -> f16 dst[n][k_off + k], dst leading dim dst_ld
__global__ __launch_bounds__(256) void k_transpose(
    const float* __restrict__ src, int K, int N,
    _Float16* __restrict__ dst, int dst_ld, int k_off) {
  __shared__ float tile[64][65];
  const int k0 = blockIdx.y * 64, n0 = blockIdx.x * 64;
  const int tx = threadIdx.x & 63, ty = threadIdx.x >> 6;
#pragma unroll
  for (int j = 0; j < 16; ++j) {
    int kr = j * 4 + ty;
    tile[kr][tx] = src[(size_t)(k0 + kr) * N + n0 + tx];
  }
  __syncthreads();
#pragma unroll
  for (int j = 0; j < 16; ++j) {
    int nr = j * 4 + ty;
    dst[(size_t)(n0 + nr) * dst_ld + k_off + k0 + tx] = (_Float16)tile[tx][nr];
  }
}

// ---- prefix scan over t of x (decay 0.75) -> U f16 [11][1024][1024]; inits
__global__ __launch_bounds__(256) void k_prep(
    const float* __restrict__ x, _Float16* __restrict__ U,
    _Float16* __restrict__ AH0, _Float16* __restrict__ AP0,
    _Float16* __restrict__ AC0, float* __restrict__ Pst,
    float* __restrict__ Cst) {
  const int id = blockIdx.x * 256 + threadIdx.x;  // 0 .. 1M-1
  const int b = id >> 10, i = id & 1023;
  const float* xb = x + (size_t)b * 12 * 1024 + i;
  float g = 0.f;
#pragma unroll
  for (int t = 0; t < 11; ++t) {
    g = xb[t * 1024] + 0.75f * g;
    U[(size_t)t * 1048576 + id] = (_Float16)g;
  }
  AH0[id] = (_Float16)0.5f;
  AP0[id] = (_Float16)0.5f;
  Pst[id] = 0.f;
  if (i < 512) {
    const int cid = b * 512 + i;
    AC0[cid] = (_Float16)0.5f;
    Cst[cid] = 0.f;
  }
}

// ---- big GEMM, K=1024, 64x64 tile, single wave, PF-1 pipeline (2 buffers).
// mode 0: oh -> AH[t=mBase>>10 + 1]: sigmoid(0.25*acc + beta*bias_h), f16
// mode 1: hp -> Q: 0.25*(acc + bias_p), f16
__global__ __launch_bounds__(64) void k_gemm_big(
    const _Float16* __restrict__ A, const _Float16* __restrict__ B,
    const float* __restrict__ bias, _Float16* __restrict__ dst, int mode) {
  __shared__ __align__(16) _Float16 sA[2 * 4096];
  __shared__ __align__(16) _Float16 sB[2 * 4096];
  const int lane = threadIdx.x;
  const int mBase = blockIdx.y * 64, nBase = blockIdx.x * 64;
  const int r16 = lane & 15, quad = lane >> 4, mrow = lane >> 3;
  const int gsw = ((lane & 7) ^ (mrow & 7)) * 8;
  const floatx4 zero = {0.f, 0.f, 0.f, 0.f};
  floatx4 acc[4][4];
#pragma unroll
  for (int i = 0; i < 4; ++i)
#pragma unroll
    for (int j = 0; j < 4; ++j) acc[i][j] = zero;

  const _Float16* Abase = A + (size_t)(mBase + mrow) * 1024 + gsw;
  const _Float16* Bbase = B + (size_t)(nBase + mrow) * 1024 + gsw;

  auto stage = [&](int kt, int buf) {
    const int k0 = kt << 6;
#pragma unroll
    for (int q = 0; q < 8; ++q)
      async_cp16(Abase + (size_t)q * 8192 + k0, sA + buf * 4096 + q * 512);
#pragma unroll
    for (int q = 0; q < 8; ++q)
      async_cp16(Bbase + (size_t)q * 8192 + k0, sB + buf * 4096 + q * 512);
  };

  stage(0, 0);
  for (int kt = 0; kt < 16; ++kt) {
    if (kt + 1 < 16) {
      stage(kt + 1, (kt + 1) & 1);
      asm volatile("s_waitcnt vmcnt(16)" ::: "memory");
    } else {
      asm volatile("s_waitcnt vmcnt(0)" ::: "memory");
    }
    const _Float16* sa = sA + (kt & 1) * 4096;
    const _Float16* sb = sB + (kt & 1) * 4096;
#pragma unroll
    for (int kk = 0; kk < 2; ++kk) {
      const int sw = ((kk * 4 + quad) ^ (r16 & 7)) * 8;
      half8 af[4], bf[4];
#pragma unroll
      for (int i = 0; i < 4; ++i) af[i] = *(const half8*)&sa[(i * 16 + r16) * 64 + sw];
#pragma unroll
      for (int j = 0; j < 4; ++j) bf[j] = *(const half8*)&sb[(j * 16 + r16) * 64 + sw];
#pragma unroll
      for (int i = 0; i < 4; ++i)
#pragma unroll
        for (int j = 0; j < 4; ++j)
          acc[i][j] =
              __builtin_amdgcn_mfma_f32_16x16x32_f16(af[i], bf[j], acc[i][j], 0, 0, 0);
    }
  }

  if (mode == 0) {
    const int tm1 = mBase >> 10;
    const float beta = 1.f - __powf(0.75f, (float)(tm1 + 1));
    _Float16* o = dst + (size_t)(mBase + 1024) * 1024;
#pragma unroll
    for (int i = 0; i < 4; ++i)
#pragma unroll
      for (int j = 0; j < 4; ++j) {
        const int n = nBase + j * 16 + r16;
#pragma unroll
        for (int r = 0; r < 4; ++r) {
          const int row = i * 16 + quad * 4 + r;
          const float h = 0.25f * acc[i][j][r] + beta * bias[n];
          o[(size_t)row * 1024 + n] = (_Float16)sigmoidf_(h);
        }
      }
  } else {
    _Float16* o = dst + (size_t)mBase * 1024;
#pragma unroll
    for (int i = 0; i < 4; ++i)
#pragma unroll
      for (int j = 0; j < 4; ++j) {
        const int n = nBase + j * 16 + r16;
#pragma unroll
        for (int r = 0; r < 4; ++r) {
          const int row = i * 16 + quad * 4 + r;
          o[(size_t)row * 1024 + n] = (_Float16)(0.25f * (acc[i][j][r] + bias[n]));
        }
      }
  }
}

// ---- one recurrent step. blockIdx.x<16: p (K=1536 over [a_p|a_c], Q added
// in epilogue); else: c (K=1024 over a_p). Single wave, 3-buffer PF-2
// pipeline, no barriers.
__global__ __launch_bounds__(64) void k_step(
    const _Float16* __restrict__ Qt, const _Float16* __restrict__ APc,
    const _Float16* __restrict__ ACc, _Float16* __restrict__ APn,
    _Float16* __restrict__ ACn, const _Float16* __restrict__ Wr,
    const _Float16* __restrict__ Wc, const float* __restrict__ bias_c,
    float* __restrict__ Pst, float* __restrict__ Cst,
    float* __restrict__ out_t) {
  __shared__ __align__(16) _Float16 sA[3 * 4096];
  __shared__ __align__(16) _Float16 sB[3 * 4096];
  const int lane = threadIdx.x;
  const int mBase = blockIdx.y * 64;
  const bool isP = blockIdx.x < 16;
  const int nBase = isP ? blockIdx.x * 64 : (blockIdx.x - 16) * 64;
  const int r16 = lane & 15, quad = lane >> 4, mrow = lane >> 3;
  const int gsw = ((lane & 7) ^ (mrow & 7)) * 8;
  const floatx4 zero = {0.f, 0.f, 0.f, 0.f};
  floatx4 acc[4][4];
#pragma unroll
  for (int i = 0; i < 4; ++i)
#pragma unroll
    for (int j = 0; j < 4; ++j) acc[i][j] = zero;

  const int KT = isP ? 24 : 16;
  const int ldB = isP ? 1536 : 1024;
  const _Float16* Bbase =
      (isP ? Wr + (size_t)nBase * 1536 : Wc + (size_t)nBase * 1024) +
      (size_t)mrow * ldB + gsw;

  auto stage = [&](int kt, int buf) {
    const int k0 = kt << 6;
    const _Float16* ap;
    size_t strA;
    if (isP && k0 >= 1024) {  // a_c segment
      ap = ACc + (size_t)(mBase + mrow) * 512 + (k0 - 1024) + gsw;
      strA = 8 * 512;
    } else {  // a_p segment
      ap = APc + (size_t)(mBase + mrow) * 1024 + k0 + gsw;
      strA = 8 * 1024;
    }
#pragma unroll
    for (int q = 0; q < 8; ++q)
      async_cp16(ap + q * strA, sA + buf * 4096 + q * 512);
    const _Float16* bp = Bbase + (size_t)k0;
#pragma unroll
    for (int q = 0; q < 8; ++q)
      async_cp16(bp + (size_t)q * 8 * ldB, sB + buf * 4096 + q * 512);
  };

  stage(0, 0);
  stage(1, 1);
  for (int kt = 0; kt < KT; ++kt) {
    if (kt + 2 < KT) {
      stage(kt + 2, (kt + 2) % 3);
      asm volatile("s_waitcnt vmcnt(32)" ::: "memory");
    } else if (kt + 1 < KT) {
      asm volatile("s_waitcnt vmcnt(16)" ::: "memory");
    } else {
      asm volatile("s_waitcnt vmcnt(0)" ::: "memory");
    }
    const _Float16* sa = sA + (kt % 3) * 4096;
    const _Float16* sb = sB + (kt % 3) * 4096;
#pragma unroll
    for (int kk = 0; kk < 2; ++kk) {
      const int sw = ((kk * 4 + quad) ^ (r16 & 7)) * 8;
      half8 af[4], bf[4];
#pragma unroll
      for (int i = 0; i < 4; ++i) af[i] = *(const half8*)&sa[(i * 16 + r16) * 64 + sw];
#pragma unroll
      for (int j = 0; j < 4; ++j) bf[j] = *(const half8*)&sb[(j * 16 + r16) * 64 + sw];
#pragma unroll
      for (int i = 0; i < 4; ++i)
#pragma unroll
        for (int j = 0; j < 4; ++j)
          acc[i][j] =
              __builtin_amdgcn_mfma_f32_16x16x32_f16(af[i], bf[j], acc[i][j], 0, 0, 0);
    }
  }

  if (isP) {
#pragma unroll
    for (int i = 0; i < 4; ++i)
#pragma unroll
      for (int j = 0; j < 4; ++j) {
        const int n = nBase + j * 16 + r16;
#pragma unroll
        for (int r = 0; r < 4; ++r) {
          const int b = mBase + i * 16 + quad * 4 + r;
          const size_t o = (size_t)b * 1024 + n;
          const float pn = 0.25f * acc[i][j][r] + (float)Qt[o] + 0.75f * Pst[o];
          Pst[o] = pn;
          const float a = sigmoidf_(pn);
          APn[o] = (_Float16)a;
          if (out_t) out_t[o] = a;
        }
      }
  } else {
#pragma unroll
    for (int i = 0; i < 4; ++i)
#pragma unroll
      for (int j = 0; j < 4; ++j) {
        const int n = nBase + j * 16 + r16;  // 0..511
#pragma unroll
        for (int r = 0; r < 4; ++r) {
          const int b = mBase + i * 16 + quad * 4 + r;
          const size_t o = (size_t)b * 512 + n;
          const float cn = 0.25f * (acc[i][j][r] + bias_c[n]) + 0.75f * Cst[o];
          Cst[o] = cn;
          ACn[o] = (_Float16)sigmoidf_(cn);
        }
      }
  }
}

extern "C" void kernel_launch(void* const* d_in, const int* in_sizes, int n_in,
                              void* d_out, int out_size, void* d_ws,
                              size_t ws_size, hipStream_t stream) {
  const float* x      = (const float*)d_in[0];  // [1024,12,1024]
  const float* w_oh   = (const float*)d_in[1];
  const float* w_hp   = (const float*)d_in[2];
  const float* w_pp   = (const float*)d_in[3];
  const float* w_pc   = (const float*)d_in[4];  // [1024,512]
  const float* w_cp   = (const float*)d_in[5];  // [512,1024]
  const float* bias_h = (const float*)d_in[6];
  const float* bias_p = (const float*)d_in[7];
  const float* bias_c = (const float*)d_in[8];
  float* out = (float*)d_out;

  uint8_t* p = (uint8_t*)d_ws;
  _Float16* Wr   = (_Float16*)p; p += (size_t)1024 * 1536 * 2;  // [n][pp|cp]
  _Float16* Wc   = (_Float16*)p; p += (size_t)512 * 1024 * 2;   // [n][k]
  _Float16* WohT = (_Float16*)p; p += (size_t)1024 * 1024 * 2;
  _Float16* Whp  = (_Float16*)p; p += (size_t)1024 * 1024 * 2;
  _Float16* U    = (_Float16*)p; p += (size_t)11 * 1048576 * 2;
  _Float16* AH   = (_Float16*)p; p += (size_t)12 * 1048576 * 2;
  _Float16* Q    = (_Float16*)p; p += (size_t)12 * 1048576 * 2;
  _Float16* AP0  = (_Float16*)p; p += (size_t)1048576 * 2;
  _Float16* AP1  = (_Float16*)p; p += (size_t)1048576 * 2;
  _Float16* AC0  = (_Float16*)p; p += (size_t)512 * 1024 * 2;
  _Float16* AC1  = (_Float16*)p; p += (size_t)512 * 1024 * 2;
  float* Pst = (float*)p; p += (size_t)1048576 * 4;
  float* Cst = (float*)p; p += (size_t)512 * 1024 * 4;

  const dim3 blk256(256), blk64(64);
  // weight repack (fp32 [K][N] -> f16 [N][K])
  k_transpose<<<dim3(16, 16), blk256, 0, stream>>>(w_pp, 1024, 1024, Wr, 1536, 0);
  k_transpose<<<dim3(16, 8),  blk256, 0, stream>>>(w_cp, 512, 1024, Wr, 1536, 1024);
  k_transpose<<<dim3(8, 16),  blk256, 0, stream>>>(w_pc, 1024, 512, Wc, 1024, 0);
  k_transpose<<<dim3(16, 16), blk256, 0, stream>>>(w_oh, 1024, 1024, WohT, 1024, 0);
  k_transpose<<<dim3(16, 16), blk256, 0, stream>>>(w_hp, 1024, 1024, Whp, 1024, 0);
  // input scan + state init
  k_prep<<<4096, blk256, 0, stream>>>(x, U, AH, AP0, AC0, Pst, Cst);
  // hoisted h GEMM -> AH[1..11]
  k_gemm_big<<<dim3(16, 176), blk64, 0, stream>>>(U, WohT, bias_h, AH, 0);
  // hoisted hp GEMM: Q_t = 0.25*(a_h_t @ w_hp + bias_p), all 12 t
  k_gemm_big<<<dim3(16, 192), blk64, 0, stream>>>(AH, Whp, bias_p, Q, 1);
  // 12 sequential steps (P: K=1536, C: K=1024)
  for (int t = 0; t < 12; ++t) {
    const _Float16* APc = (t & 1) ? AP1 : AP0;
    _Float16* APn       = (t & 1) ? AP0 : AP1;
    const _Float16* ACc = (t & 1) ? AC1 : AC0;
    _Float16* ACn       = (t & 1) ? AC0 : AC1;
    float* ot = (t >= 8) ? out + (size_t)(t - 8) * 1048576 : (float*)nullptr;
    k_step<<<dim3(24, 16), blk64, 0, stream>>>(Q + (size_t)t * 1048576, APc,
                                               ACc, APn, ACn, Wr, Wc, bias_c,
                                               Pst, Cst, ot);
  }
}